// Round 20
// baseline (143.803 us; speedup 1.0000x reference)
//
#include <hip/hip_runtime.h>
#include <hip/hip_bf16.h>

// SelfAttention: B=8, C=512, W=2048, CR=64
// castT(128x128)/cast_w -> proj_qk2 -> qk_expf8 (S^T -> fp8 P frag-major + il)
//   -> proj_v2f8 (fp8 v' = v*il*1024) -> pv38 (fp8 GEMM, 8 waves, 2-deep prefetch).

#define B 8
#define C 512
#define W 2048
#define CR 64
static constexpr float SCALE = 0.125f; // 64^-0.5

typedef __bf16 bf16x8 __attribute__((ext_vector_type(8)));
typedef float f32x4 __attribute__((ext_vector_type(4)));
typedef unsigned char uchar;
typedef unsigned long long ull;

__device__ inline ushort f2bs(float f) {
    __hip_bfloat16 h = __float2bfloat16(f);
    return *reinterpret_cast<ushort*>(&h);
}
__device__ inline f32x4 mfma16(bf16x8 a, bf16x8 b, f32x4 c) {
    return __builtin_amdgcn_mfma_f32_16x16x32_bf16(a, b, c, 0, 0, 0);
}
__device__ inline f32x4 mfma8(long long a, long long b, f32x4 c) {
    return __builtin_amdgcn_mfma_f32_16x16x32_fp8_fp8(a, b, c, 0, 0, 0);
}

// f32 -> OCP e4m3 byte
__device__ inline uchar f2fp8(float f) {
#if __has_builtin(__builtin_amdgcn_cvt_pk_fp8_f32)
    int v = __builtin_amdgcn_cvt_pk_fp8_f32(f, f, 0, false);
    return (uchar)(v & 0xFF);
#else
    unsigned u = __float_as_uint(f);
    uchar s = (uchar)((u >> 24) & 0x80);
    float a = fabsf(f);
    if (a >= 448.0f) return s | 0x7E;
    if (a < 0.015625f) {
        int m = (int)rintf(a * 512.0f);
        if (m > 7) return s | 0x08;
        return s | (uchar)m;
    }
    int e; float m = frexpf(a, &e);
    int Eb = e - 1 + 7;
    int mant = (int)rintf((m * 2.0f - 1.0f) * 8.0f);
    if (mant == 8) { mant = 0; Eb++; }
    if (Eb > 15 || (Eb == 15 && mant > 6)) return s | 0x7E;
    return s | (uchar)(Eb << 3) | (uchar)mant;
#endif
}

// fp8 frag-major tile layout (1KB per 16row x 64k tile)
__device__ inline size_t vpf8_idx(int b, int c, int i) {
    return (((size_t)(b * 32 + (i >> 6)) * 32 + (c >> 4)) << 10)
         + (((i >> 5) & 1) << 9) + ((((c & 15) | (((i >> 3) & 3) << 4))) << 3) + (i & 7);
}

// ================= pre-pass kernels =================

__global__ __launch_bounds__(256) void cast_w(
    const float* __restrict__ wq, const float* __restrict__ wk, const float* __restrict__ wv,
    ushort* __restrict__ wqb, ushort* __restrict__ wkb, ushort* __restrict__ wvb)
{
    int i = blockIdx.x * 256 + threadIdx.x;
    if (i < CR * C) { wqb[i] = f2bs(wq[i]); wkb[i] = f2bs(wk[i]); }
    if (i < C * C)  { wvb[i] = f2bs(wv[i]); }
}

// castT v2: 128c x 128w tiles; float4 reads (512B rows), 256B contiguous writes.
__global__ __launch_bounds__(256) void castT_kernel(
    const float* __restrict__ x, ushort* __restrict__ xb)
{
    __shared__ __align__(16) ushort tile[128][136];
    const int b = blockIdx.z, c0 = blockIdx.y * 128, w0 = blockIdx.x * 128;
    const int t = threadIdx.x;
    // read: 128 rows x 32 float4 = 4096 units
    for (int idx = t; idx < 128 * 32; idx += 256) {
        int c = idx >> 5, u = idx & 31;
        f32x4 v4 = *(const f32x4*)&x[((size_t)b * C + c0 + c) * W + w0 + u * 4];
        int w = u * 4;
        tile[w + 0][c] = f2bs(v4[0]);
        tile[w + 1][c] = f2bs(v4[1]);
        tile[w + 2][c] = f2bs(v4[2]);
        tile[w + 3][c] = f2bs(v4[3]);
    }
    __syncthreads();
    // write: 128 w-rows x 16 bf16x8 = 2048 units (256B contiguous per row)
    for (int idx = t; idx < 128 * 16; idx += 256) {
        int w = idx >> 4, u = idx & 15;
        *(bf16x8*)&xb[((size_t)b * W + w0 + w) * C + c0 + u * 8] = *(const bf16x8*)&tile[w][u * 8];
    }
}

__global__ __launch_bounds__(128) void proj_qk2_kernel(
    const ushort* __restrict__ xb, const ushort* __restrict__ wqb, const ushort* __restrict__ wkb,
    const float* __restrict__ bqf, const float* __restrict__ bkf,
    ushort* __restrict__ qT, ushort* __restrict__ kT)
{
    const int bid = blockIdx.x;
    const int b = bid & 7;
    const int w0 = (bid >> 3) * 64 + (threadIdx.x >> 6) * 32;
    const int lane = threadIdx.x & 63;
    const int lr = lane & 15, lg = lane >> 4;

    f32x4 accq[2][4] = {};
    f32x4 acck[2][4] = {};
    for (int kk = 0; kk < 16; ++kk) {
        const int ko = kk * 32 + (lg << 3);
        bf16x8 a[2], fq[4], fk[4];
        #pragma unroll
        for (int mf = 0; mf < 2; ++mf)
            a[mf] = *(const bf16x8*)&xb[((size_t)b * W + w0 + mf * 16 + lr) * C + ko];
        #pragma unroll
        for (int nf = 0; nf < 4; ++nf) {
            fq[nf] = *(const bf16x8*)&wqb[(nf * 16 + lr) * C + ko];
            fk[nf] = *(const bf16x8*)&wkb[(nf * 16 + lr) * C + ko];
        }
        #pragma unroll
        for (int mf = 0; mf < 2; ++mf)
            #pragma unroll
            for (int nf = 0; nf < 4; ++nf) {
                accq[mf][nf] = mfma16(a[mf], fq[nf], accq[mf][nf]);
                acck[mf][nf] = mfma16(a[mf], fk[nf], acck[mf][nf]);
            }
    }
    #pragma unroll
    for (int nf = 0; nf < 4; ++nf) {
        const int d = nf * 16 + lr;
        const float bqv = bqf[d], bkv = bkf[d];
        #pragma unroll
        for (int mf = 0; mf < 2; ++mf)
            #pragma unroll
            for (int r = 0; r < 4; ++r) {
                int w = w0 + mf * 16 + (lg << 2) + r;
                qT[(b * W + w) * CR + d] = f2bs(accq[mf][nf][r] + bqv);
                kT[(b * W + w) * CR + d] = f2bs(acck[mf][nf][r] + bkv);
            }
    }
}

// ================= qk_expf8: S^T -> fp8 P (frag-major) + il =================
__global__ __launch_bounds__(512) void qk_expf8_kernel(
    const ushort* __restrict__ qT, const ushort* __restrict__ kT,
    uchar* __restrict__ PuF8, float* __restrict__ ilrow)
{
    __shared__ __align__(8) uchar ptb[8][64][72];
    __shared__ float red[8][64];
    const int bid = blockIdx.x;
    const int b = bid & 7;
    const int i0 = (bid >> 3) * 64;
    const int it = i0 >> 6;
    const int t = threadIdx.x;
    const int w = t >> 6, lane = t & 63;
    const int lr = lane & 15, lg = lane >> 4;

    bf16x8 bq[4][2];
    #pragma unroll
    for (int nf = 0; nf < 4; ++nf)
        #pragma unroll
        for (int kk = 0; kk < 2; ++kk)
            bq[nf][kk] = *(const bf16x8*)&qT[(b * W + i0 + nf * 16 + lr) * CR + kk * 32 + (lg << 3)];

    float lacc[4] = {0.f, 0.f, 0.f, 0.f};
    for (int jt = 0; jt < 4; ++jt) {
        const int j0 = (jt * 8 + w) * 64;
        #pragma unroll
        for (int mf = 0; mf < 4; ++mf) {
            bf16x8 akf[2];
            #pragma unroll
            for (int kk = 0; kk < 2; ++kk)
                akf[kk] = *(const bf16x8*)&kT[(b * W + j0 + mf * 16 + lr) * CR + kk * 32 + (lg << 3)];
            f32x4 s[4] = {};
            #pragma unroll
            for (int kk = 0; kk < 2; ++kk)
                #pragma unroll
                for (int nf = 0; nf < 4; ++nf)
                    s[nf] = mfma16(akf[kk], bq[nf][kk], s[nf]);
            #pragma unroll
            for (int nf = 0; nf < 4; ++nf)
                #pragma unroll
                for (int r = 0; r < 4; ++r) {
                    float e = __expf(s[nf][r] * SCALE);
                    lacc[nf] += e;
                    ptb[w][mf * 16 + (lg << 2) + r][nf * 16 + lr] = f2fp8(e);
                }
        }
        #pragma unroll
        for (int mf = 0; mf < 4; ++mf) {
            const int jl = mf * 16 + (lane & 15);
            const size_t tbase = (((size_t)(b * 32 + it) * 128 + (j0 >> 4) + mf) << 10);
            #pragma unroll
            for (int kk = 0; kk < 2; ++kk) {
                const int ikb = (kk << 5) | ((lane >> 4) << 3);
                ull val = *(const ull*)&ptb[w][jl][ikb];
                *(ull*)&PuF8[tbase + (kk << 9) + ((size_t)lane << 3)] = val;
            }
        }
    }
    #pragma unroll
    for (int nf = 0; nf < 4; ++nf) {
        lacc[nf] += __shfl_xor(lacc[nf], 16);
        lacc[nf] += __shfl_xor(lacc[nf], 32);
        if (lg == 0) red[w][nf * 16 + lr] = lacc[nf];
    }
    __syncthreads();
    if (t < 64) {
        float ll = 0.f;
        #pragma unroll
        for (int g = 0; g < 8; ++g) ll += red[g][t];
        ilrow[b * W + i0 + t] = 1.0f / ll;
    }
}

// ============ proj_v2f8: v' = (wv@x + bv) * il * 1024, fp8 frag-major ========
__global__ __launch_bounds__(512) void proj_v2f8_kernel(
    const ushort* __restrict__ xb, const ushort* __restrict__ wvb, const float* __restrict__ bvf,
    const float* __restrict__ ilw, uchar* __restrict__ vpF8)
{
    const int bid = blockIdx.x;
    const int b = bid & 7;
    const int ct = (bid >> 3) & 3;
    const int wt = bid >> 5;
    const int wid = threadIdx.x >> 6, lane = threadIdx.x & 63;
    const int c0 = ct * 128 + (wid >> 2) * 64;
    const int w0 = wt * 256 + (wid & 3) * 64;
    const int lr = lane & 15, lg = lane >> 4;

    f32x4 acc[4][4] = {};
    for (int kk = 0; kk < 16; ++kk) {
        const int ko = kk * 32 + (lg << 3);
        bf16x8 a[4], bb[4];
        #pragma unroll
        for (int mf = 0; mf < 4; ++mf)
            a[mf] = *(const bf16x8*)&wvb[(c0 + mf * 16 + lr) * C + ko];
        #pragma unroll
        for (int nf = 0; nf < 4; ++nf)
            bb[nf] = *(const bf16x8*)&xb[((size_t)b * W + w0 + nf * 16 + lr) * C + ko];
        #pragma unroll
        for (int mf = 0; mf < 4; ++mf)
            #pragma unroll
            for (int nf = 0; nf < 4; ++nf)
                acc[mf][nf] = mfma16(a[mf], bb[nf], acc[mf][nf]);
    }
    float ilv[4];
    #pragma unroll
    for (int nf = 0; nf < 4; ++nf)
        ilv[nf] = ilw[b * W + w0 + nf * 16 + lr] * 1024.0f;
    #pragma unroll
    for (int mf = 0; mf < 4; ++mf) {
        #pragma unroll
        for (int r = 0; r < 4; ++r) {
            const int c = c0 + mf * 16 + (lg << 2) + r;
            const float bvv = bvf[c];
            #pragma unroll
            for (int nf = 0; nf < 4; ++nf) {
                int w = w0 + nf * 16 + lr;
                vpF8[vpf8_idx(b, c, w)] = f2fp8((acc[mf][nf][r] + bvv) * ilv[nf]);
            }
        }
    }
}

// ===== pv38 v3: 8 waves x 64c, 4x4 tile, 2-deep prefetch, grid 256. =====
__global__ __launch_bounds__(512) void pv38_kernel(
    const float* __restrict__ x, const uchar* __restrict__ vpF8, const uchar* __restrict__ PuF8,
    float* __restrict__ out)
{
    const int bid = blockIdx.x;
    const int b = bid & 7;
    const int j0 = (bid >> 3) * 64;
    const int w = threadIdx.x >> 6, lane = threadIdx.x & 63;
    const int lr = lane & 15, lg = lane >> 4;
    const int c0 = w * 64;
    const int ct0 = c0 >> 4;
    const int jt0 = j0 >> 4;
    const int NIT = W / 64;
    const int lo = lane * 8;

    long long a_cur[4][2], a_n1[4][2], a_n2[4][2];
    long long b_cur[4][2], b_n1[4][2], b_n2[4][2];
    #pragma unroll
    for (int mf = 0; mf < 4; ++mf)
        #pragma unroll
        for (int kk = 0; kk < 2; ++kk) {
            a_cur[mf][kk] = *(const long long*)&vpF8[(((size_t)(b * 32 + 0) * 32 + ct0 + mf) << 10) + (kk << 9) + lo];
            a_n1[mf][kk]  = *(const long long*)&vpF8[(((size_t)(b * 32 + 1) * 32 + ct0 + mf) << 10) + (kk << 9) + lo];
        }
    #pragma unroll
    for (int nf = 0; nf < 4; ++nf)
        #pragma unroll
        for (int kk = 0; kk < 2; ++kk) {
            b_cur[nf][kk] = *(const long long*)&PuF8[(((size_t)(b * 32 + 0) * 128 + jt0 + nf) << 10) + (kk << 9) + lo];
            b_n1[nf][kk]  = *(const long long*)&PuF8[(((size_t)(b * 32 + 1) * 128 + jt0 + nf) << 10) + (kk << 9) + lo];
        }

    f32x4 acc[4][4] = {};
    for (int it = 0; it < NIT; ++it) {
        const int in = (it + 2 < NIT) ? (it + 2) : (NIT - 1);
        #pragma unroll
        for (int mf = 0; mf < 4; ++mf)
            #pragma unroll
            for (int kk = 0; kk < 2; ++kk)
                a_n2[mf][kk] = *(const long long*)&vpF8[(((size_t)(b * 32 + in) * 32 + ct0 + mf) << 10) + (kk << 9) + lo];
        #pragma unroll
        for (int nf = 0; nf < 4; ++nf)
            #pragma unroll
            for (int kk = 0; kk < 2; ++kk)
                b_n2[nf][kk] = *(const long long*)&PuF8[(((size_t)(b * 32 + in) * 128 + jt0 + nf) << 10) + (kk << 9) + lo];
        #pragma unroll
        for (int kk = 0; kk < 2; ++kk)
            #pragma unroll
            for (int mf = 0; mf < 4; ++mf)
                #pragma unroll
                for (int nf = 0; nf < 4; ++nf)
                    acc[mf][nf] = mfma8(a_cur[mf][kk], b_cur[nf][kk], acc[mf][nf]);
        #pragma unroll
        for (int mf = 0; mf < 4; ++mf)
            #pragma unroll
            for (int kk = 0; kk < 2; ++kk) {
                a_cur[mf][kk] = a_n1[mf][kk];
                a_n1[mf][kk]  = a_n2[mf][kk];
            }
        #pragma unroll
        for (int nf = 0; nf < 4; ++nf)
            #pragma unroll
            for (int kk = 0; kk < 2; ++kk) {
                b_cur[nf][kk] = b_n1[nf][kk];
                b_n1[nf][kk]  = b_n2[nf][kk];
            }
    }
    #pragma unroll
    for (int mf = 0; mf < 4; ++mf)
        #pragma unroll
        for (int nf = 0; nf < 4; ++nf)
            #pragma unroll
            for (int r = 0; r < 4; ++r) {
                int c = c0 + mf * 16 + (lg << 2) + r;
                int j = j0 + nf * 16 + lr;
                int off = (b * C + c) * W + j;
                out[off] = acc[mf][nf][r] * 0.0009765625f + x[off];
            }
}

extern "C" void kernel_launch(void* const* d_in, const int* in_sizes, int n_in,
                              void* d_out, int out_size, void* d_ws, size_t ws_size,
                              hipStream_t stream) {
    const float* x  = (const float*)d_in[0];
    const float* wq = (const float*)d_in[1];
    const float* bq = (const float*)d_in[2];
    const float* wk = (const float*)d_in[3];
    const float* bk = (const float*)d_in[4];
    const float* wv = (const float*)d_in[5];
    const float* bv = (const float*)d_in[6];
    float* out = (float*)d_out;

    char* ws = (char*)d_ws;
    ushort* qTw  = (ushort*)(ws);                               // 2 MB
    ushort* kTw  = (ushort*)(ws + (2u << 20));                  // 2 MB
    uchar*  vpF8 = (uchar*)(ws + (4u << 20));                   // 8 MB -> ends 12MB
    ushort* xbw  = (ushort*)(ws + (20u << 20));                 // 16 MB -> ends 36MB
    ushort* wqb  = (ushort*)(ws + (36u << 20));                 // 64 KB
    ushort* wkb  = (ushort*)(ws + (36u << 20) + (64u << 10));   // 64 KB
    ushort* wvb  = (ushort*)(ws + (36u << 20) + (128u << 10));  // 512 KB
    float*  ilrw = (float*)(ws + (36u << 20) + (640u << 10));   // 64 KB
    uchar*  PuF8 = (uchar*)(ws + (37u << 20));                  // 32 MB -> ends 69MB

    cast_w<<<dim3(1024), 256, 0, stream>>>(wq, wk, wv, wqb, wkb, wvb);
    castT_kernel<<<dim3(W / 128, C / 128, B), 256, 0, stream>>>(x, xbw);
    proj_qk2_kernel<<<dim3(W / 64 * B), 128, 0, stream>>>(xbw, wqb, wkb, bq, bk, qTw, kTw);
    qk_expf8_kernel<<<dim3(W / 64 * B), 512, 0, stream>>>(qTw, kTw, PuF8, ilrw);
    proj_v2f8_kernel<<<dim3(W / 256 * (C / 128) * B), 512, 0, stream>>>(xbw, wvb, bv, ilrw, vpF8);
    pv38_kernel<<<dim3(W / 64 * B), 512, 0, stream>>>(x, vpF8, PuF8, out);
}

// Round 21
// 126.947 us; speedup vs baseline: 1.1328x; 1.1328x over previous
//
#include <hip/hip_runtime.h>
#include <hip/hip_bf16.h>

// SelfAttention: B=8, C=512, W=2048, CR=64  (round-18 proven config)
// castT/cast_w -> proj_qk2 (bf16 MFMA) -> qk_expf8 (S^T -> fp8 P, frag-major,
//   + il) -> proj_v2f8 (bf16 MFMA, epilogue fp8 v' = v*il*1024) -> pv38
//   (fp8 MFMA GEMM, j=64 4x4 shape, 1-deep prefetch, epilogue acc/1024 + x).

#define B 8
#define C 512
#define W 2048
#define CR 64
static constexpr float SCALE = 0.125f; // 64^-0.5

typedef __bf16 bf16x8 __attribute__((ext_vector_type(8)));
typedef float f32x4 __attribute__((ext_vector_type(4)));
typedef unsigned char uchar;
typedef unsigned long long ull;

__device__ inline ushort f2bs(float f) {
    __hip_bfloat16 h = __float2bfloat16(f);
    return *reinterpret_cast<ushort*>(&h);
}
__device__ inline f32x4 mfma16(bf16x8 a, bf16x8 b, f32x4 c) {
    return __builtin_amdgcn_mfma_f32_16x16x32_bf16(a, b, c, 0, 0, 0);
}
__device__ inline f32x4 mfma8(long long a, long long b, f32x4 c) {
    return __builtin_amdgcn_mfma_f32_16x16x32_fp8_fp8(a, b, c, 0, 0, 0);
}

// f32 -> OCP e4m3 byte
__device__ inline uchar f2fp8(float f) {
#if __has_builtin(__builtin_amdgcn_cvt_pk_fp8_f32)
    int v = __builtin_amdgcn_cvt_pk_fp8_f32(f, f, 0, false);
    return (uchar)(v & 0xFF);
#else
    unsigned u = __float_as_uint(f);
    uchar s = (uchar)((u >> 24) & 0x80);
    float a = fabsf(f);
    if (a >= 448.0f) return s | 0x7E;
    if (a < 0.015625f) {
        int m = (int)rintf(a * 512.0f);
        if (m > 7) return s | 0x08;
        return s | (uchar)m;
    }
    int e; float m = frexpf(a, &e);
    int Eb = e - 1 + 7;
    int mant = (int)rintf((m * 2.0f - 1.0f) * 8.0f);
    if (mant == 8) { mant = 0; Eb++; }
    if (Eb > 15 || (Eb == 15 && mant > 6)) return s | 0x7E;
    return s | (uchar)(Eb << 3) | (uchar)mant;
#endif
}

// fp8 frag-major tile layout (1KB per 16row x 64k tile)
__device__ inline size_t vpf8_idx(int b, int c, int i) {
    return (((size_t)(b * 32 + (i >> 6)) * 32 + (c >> 4)) << 10)
         + (((i >> 5) & 1) << 9) + ((((c & 15) | (((i >> 3) & 3) << 4))) << 3) + (i & 7);
}

// ================= pre-pass kernels =================

__global__ __launch_bounds__(256) void cast_w(
    const float* __restrict__ wq, const float* __restrict__ wk, const float* __restrict__ wv,
    ushort* __restrict__ wqb, ushort* __restrict__ wkb, ushort* __restrict__ wvb)
{
    int i = blockIdx.x * 256 + threadIdx.x;
    if (i < CR * C) { wqb[i] = f2bs(wq[i]); wkb[i] = f2bs(wk[i]); }
    if (i < C * C)  { wvb[i] = f2bs(wv[i]); }
}

__global__ __launch_bounds__(256) void castT_kernel(
    const float* __restrict__ x, ushort* __restrict__ xb)
{
    __shared__ __align__(16) ushort tile[64][72];
    const int b = blockIdx.z, c0 = blockIdx.y * 64, w0 = blockIdx.x * 64;
    const int t = threadIdx.x;
    for (int idx = t; idx < 64 * 64; idx += 256) {
        int c = idx >> 6, w = idx & 63;
        tile[w][c] = f2bs(x[(b * C + c0 + c) * W + w0 + w]);
    }
    __syncthreads();
    for (int idx = t; idx < 64 * 8; idx += 256) {
        int w = idx >> 3, u = idx & 7;
        *(bf16x8*)&xb[((size_t)b * W + w0 + w) * C + c0 + u * 8] = *(const bf16x8*)&tile[w][u * 8];
    }
}

__global__ __launch_bounds__(128) void proj_qk2_kernel(
    const ushort* __restrict__ xb, const ushort* __restrict__ wqb, const ushort* __restrict__ wkb,
    const float* __restrict__ bqf, const float* __restrict__ bkf,
    ushort* __restrict__ qT, ushort* __restrict__ kT)
{
    const int bid = blockIdx.x;
    const int b = bid & 7;
    const int w0 = (bid >> 3) * 64 + (threadIdx.x >> 6) * 32;
    const int lane = threadIdx.x & 63;
    const int lr = lane & 15, lg = lane >> 4;

    f32x4 accq[2][4] = {};
    f32x4 acck[2][4] = {};
    for (int kk = 0; kk < 16; ++kk) {
        const int ko = kk * 32 + (lg << 3);
        bf16x8 a[2], fq[4], fk[4];
        #pragma unroll
        for (int mf = 0; mf < 2; ++mf)
            a[mf] = *(const bf16x8*)&xb[((size_t)b * W + w0 + mf * 16 + lr) * C + ko];
        #pragma unroll
        for (int nf = 0; nf < 4; ++nf) {
            fq[nf] = *(const bf16x8*)&wqb[(nf * 16 + lr) * C + ko];
            fk[nf] = *(const bf16x8*)&wkb[(nf * 16 + lr) * C + ko];
        }
        #pragma unroll
        for (int mf = 0; mf < 2; ++mf)
            #pragma unroll
            for (int nf = 0; nf < 4; ++nf) {
                accq[mf][nf] = mfma16(a[mf], fq[nf], accq[mf][nf]);
                acck[mf][nf] = mfma16(a[mf], fk[nf], acck[mf][nf]);
            }
    }
    #pragma unroll
    for (int nf = 0; nf < 4; ++nf) {
        const int d = nf * 16 + lr;
        const float bqv = bqf[d], bkv = bkf[d];
        #pragma unroll
        for (int mf = 0; mf < 2; ++mf)
            #pragma unroll
            for (int r = 0; r < 4; ++r) {
                int w = w0 + mf * 16 + (lg << 2) + r;
                qT[(b * W + w) * CR + d] = f2bs(accq[mf][nf][r] + bqv);
                kT[(b * W + w) * CR + d] = f2bs(acck[mf][nf][r] + bkv);
            }
    }
}

// ================= qk_expf8: S^T -> fp8 P (frag-major) + il =================
__global__ __launch_bounds__(512) void qk_expf8_kernel(
    const ushort* __restrict__ qT, const ushort* __restrict__ kT,
    uchar* __restrict__ PuF8, float* __restrict__ ilrow)
{
    __shared__ __align__(8) uchar ptb[8][64][72]; // per-wave private P tile [j][i], fp8
    __shared__ float red[8][64];
    const int bid = blockIdx.x;
    const int b = bid & 7;
    const int i0 = (bid >> 3) * 64;
    const int it = i0 >> 6;
    const int t = threadIdx.x;
    const int w = t >> 6, lane = t & 63;
    const int lr = lane & 15, lg = lane >> 4;

    bf16x8 bq[4][2];
    #pragma unroll
    for (int nf = 0; nf < 4; ++nf)
        #pragma unroll
        for (int kk = 0; kk < 2; ++kk)
            bq[nf][kk] = *(const bf16x8*)&qT[(b * W + i0 + nf * 16 + lr) * CR + kk * 32 + (lg << 3)];

    float lacc[4] = {0.f, 0.f, 0.f, 0.f};
    for (int jt = 0; jt < 4; ++jt) {
        const int j0 = (jt * 8 + w) * 64;
        // phase 1: S^T (64j x 64i) -> private fp8 LDS tile
        #pragma unroll
        for (int mf = 0; mf < 4; ++mf) {
            bf16x8 akf[2];
            #pragma unroll
            for (int kk = 0; kk < 2; ++kk)
                akf[kk] = *(const bf16x8*)&kT[(b * W + j0 + mf * 16 + lr) * CR + kk * 32 + (lg << 3)];
            f32x4 s[4] = {};
            #pragma unroll
            for (int kk = 0; kk < 2; ++kk)
                #pragma unroll
                for (int nf = 0; nf < 4; ++nf)
                    s[nf] = mfma16(akf[kk], bq[nf][kk], s[nf]);
            #pragma unroll
            for (int nf = 0; nf < 4; ++nf)
                #pragma unroll
                for (int r = 0; r < 4; ++r) {
                    float e = __expf(s[nf][r] * SCALE);
                    lacc[nf] += e;
                    ptb[w][mf * 16 + (lg << 2) + r][nf * 16 + lr] = f2fp8(e);
                }
        }
        // phase 2: LDS -> frag-major 8B contiguous stores (512B/instr/wave)
        #pragma unroll
        for (int mf = 0; mf < 4; ++mf) {
            const int jl = mf * 16 + (lane & 15);
            const size_t tbase = (((size_t)(b * 32 + it) * 128 + (j0 >> 4) + mf) << 10);
            #pragma unroll
            for (int kk = 0; kk < 2; ++kk) {
                const int ikb = (kk << 5) | ((lane >> 4) << 3);
                ull val = *(const ull*)&ptb[w][jl][ikb];
                *(ull*)&PuF8[tbase + (kk << 9) + ((size_t)lane << 3)] = val;
            }
        }
    }
    #pragma unroll
    for (int nf = 0; nf < 4; ++nf) {
        lacc[nf] += __shfl_xor(lacc[nf], 16);
        lacc[nf] += __shfl_xor(lacc[nf], 32);
        if (lg == 0) red[w][nf * 16 + lr] = lacc[nf];
    }
    __syncthreads();
    if (t < 64) {
        float ll = 0.f;
        #pragma unroll
        for (int g = 0; g < 8; ++g) ll += red[g][t];
        ilrow[b * W + i0 + t] = 1.0f / ll;
    }
}

// ============ proj_v2f8: v' = (wv@x + bv) * il * 1024, fp8 frag-major ========
__global__ __launch_bounds__(512) void proj_v2f8_kernel(
    const ushort* __restrict__ xb, const ushort* __restrict__ wvb, const float* __restrict__ bvf,
    const float* __restrict__ ilw, uchar* __restrict__ vpF8)
{
    const int bid = blockIdx.x;
    const int b = bid & 7;
    const int ct = (bid >> 3) & 3;
    const int wt = bid >> 5;
    const int wid = threadIdx.x >> 6, lane = threadIdx.x & 63;
    const int c0 = ct * 128 + (wid >> 2) * 64;
    const int w0 = wt * 256 + (wid & 3) * 64;
    const int lr = lane & 15, lg = lane >> 4;

    f32x4 acc[4][4] = {};
    for (int kk = 0; kk < 16; ++kk) {
        const int ko = kk * 32 + (lg << 3);
        bf16x8 a[4], bb[4];
        #pragma unroll
        for (int mf = 0; mf < 4; ++mf)
            a[mf] = *(const bf16x8*)&wvb[(c0 + mf * 16 + lr) * C + ko];
        #pragma unroll
        for (int nf = 0; nf < 4; ++nf)
            bb[nf] = *(const bf16x8*)&xb[((size_t)b * W + w0 + nf * 16 + lr) * C + ko];
        #pragma unroll
        for (int mf = 0; mf < 4; ++mf)
            #pragma unroll
            for (int nf = 0; nf < 4; ++nf)
                acc[mf][nf] = mfma16(a[mf], bb[nf], acc[mf][nf]);
    }
    float ilv[4];
    #pragma unroll
    for (int nf = 0; nf < 4; ++nf)
        ilv[nf] = ilw[b * W + w0 + nf * 16 + lr] * 1024.0f;
    #pragma unroll
    for (int mf = 0; mf < 4; ++mf) {
        #pragma unroll
        for (int r = 0; r < 4; ++r) {
            const int c = c0 + mf * 16 + (lg << 2) + r;
            const float bvv = bvf[c];
            #pragma unroll
            for (int nf = 0; nf < 4; ++nf) {
                int w = w0 + nf * 16 + lr;
                vpF8[vpf8_idx(b, c, w)] = f2fp8((acc[mf][nf][r] + bvv) * ilv[nf]);
            }
        }
    }
}

// ========== pv38: fp8 GEMM, proven shape (j=64, 8 waves x 64c, 4x4) ==========
__global__ __launch_bounds__(512, 2) void pv38_kernel(
    const float* __restrict__ x, const uchar* __restrict__ vpF8, const uchar* __restrict__ PuF8,
    float* __restrict__ out)
{
    const int bid = blockIdx.x;
    const int b = bid & 7;
    const int j0 = (bid >> 3) * 64;
    const int w = threadIdx.x >> 6, lane = threadIdx.x & 63;
    const int lr = lane & 15, lg = lane >> 4;
    const int c0 = w * 64;
    const int ct0 = c0 >> 4;
    const int jt0 = j0 >> 4;
    const int NIT = W / 64;
    const int lo = lane * 8;

    long long a_cur[4][2], a_nxt[4][2], b_cur[4][2], b_nxt[4][2];
    #pragma unroll
    for (int mf = 0; mf < 4; ++mf)
        #pragma unroll
        for (int kk = 0; kk < 2; ++kk)
            a_cur[mf][kk] = *(const long long*)&vpF8[(((size_t)(b * 32 + 0) * 32 + ct0 + mf) << 10) + (kk << 9) + lo];
    #pragma unroll
    for (int nf = 0; nf < 4; ++nf)
        #pragma unroll
        for (int kk = 0; kk < 2; ++kk)
            b_cur[nf][kk] = *(const long long*)&PuF8[(((size_t)(b * 32 + 0) * 128 + jt0 + nf) << 10) + (kk << 9) + lo];

    f32x4 acc[4][4] = {};
    for (int it = 0; it < NIT; ++it) {
        const int in = (it + 1 < NIT) ? (it + 1) : it;
        #pragma unroll
        for (int mf = 0; mf < 4; ++mf)
            #pragma unroll
            for (int kk = 0; kk < 2; ++kk)
                a_nxt[mf][kk] = *(const long long*)&vpF8[(((size_t)(b * 32 + in) * 32 + ct0 + mf) << 10) + (kk << 9) + lo];
        #pragma unroll
        for (int nf = 0; nf < 4; ++nf)
            #pragma unroll
            for (int kk = 0; kk < 2; ++kk)
                b_nxt[nf][kk] = *(const long long*)&PuF8[(((size_t)(b * 32 + in) * 128 + jt0 + nf) << 10) + (kk << 9) + lo];
        #pragma unroll
        for (int kk = 0; kk < 2; ++kk)
            #pragma unroll
            for (int mf = 0; mf < 4; ++mf)
                #pragma unroll
                for (int nf = 0; nf < 4; ++nf)
                    acc[mf][nf] = mfma8(a_cur[mf][kk], b_cur[nf][kk], acc[mf][nf]);
        #pragma unroll
        for (int mf = 0; mf < 4; ++mf)
            #pragma unroll
            for (int kk = 0; kk < 2; ++kk)
                a_cur[mf][kk] = a_nxt[mf][kk];
        #pragma unroll
        for (int nf = 0; nf < 4; ++nf)
            #pragma unroll
            for (int kk = 0; kk < 2; ++kk)
                b_cur[nf][kk] = b_nxt[nf][kk];
    }
    #pragma unroll
    for (int mf = 0; mf < 4; ++mf)
        #pragma unroll
        for (int nf = 0; nf < 4; ++nf)
            #pragma unroll
            for (int r = 0; r < 4; ++r) {
                int c = c0 + mf * 16 + (lg << 2) + r;
                int j = j0 + nf * 16 + lr;
                int off = (b * C + c) * W + j;
                out[off] = acc[mf][nf][r] * 0.0009765625f + x[off];
            }
}

extern "C" void kernel_launch(void* const* d_in, const int* in_sizes, int n_in,
                              void* d_out, int out_size, void* d_ws, size_t ws_size,
                              hipStream_t stream) {
    const float* x  = (const float*)d_in[0];
    const float* wq = (const float*)d_in[1];
    const float* bq = (const float*)d_in[2];
    const float* wk = (const float*)d_in[3];
    const float* bk = (const float*)d_in[4];
    const float* wv = (const float*)d_in[5];
    const float* bv = (const float*)d_in[6];
    float* out = (float*)d_out;

    char* ws = (char*)d_ws;
    ushort* qTw  = (ushort*)(ws);                               // 2 MB
    ushort* kTw  = (ushort*)(ws + (2u << 20));                  // 2 MB
    uchar*  vpF8 = (uchar*)(ws + (4u << 20));                   // 8 MB -> ends 12MB
    ushort* xbw  = (ushort*)(ws + (20u << 20));                 // 16 MB -> ends 36MB
    ushort* wqb  = (ushort*)(ws + (36u << 20));                 // 64 KB
    ushort* wkb  = (ushort*)(ws + (36u << 20) + (64u << 10));   // 64 KB
    ushort* wvb  = (ushort*)(ws + (36u << 20) + (128u << 10));  // 512 KB
    float*  ilrw = (float*)(ws + (36u << 20) + (640u << 10));   // 64 KB
    uchar*  PuF8 = (uchar*)(ws + (37u << 20));                  // 32 MB -> ends 69MB

    cast_w<<<dim3(1024), 256, 0, stream>>>(wq, wk, wv, wqb, wkb, wvb);
    castT_kernel<<<dim3(W / 64, C / 64, B), 256, 0, stream>>>(x, xbw);
    proj_qk2_kernel<<<dim3(W / 64 * B), 128, 0, stream>>>(xbw, wqb, wkb, bq, bk, qTw, kTw);
    qk_expf8_kernel<<<dim3(W / 64 * B), 512, 0, stream>>>(qTw, kTw, PuF8, ilrw);
    proj_v2f8_kernel<<<dim3(W / 256 * (C / 128) * B), 512, 0, stream>>>(xbw, wvb, bv, ilrw, vpF8);
    pv38_kernel<<<dim3(W / 64 * B), 512, 0, stream>>>(x, vpF8, PuF8, out);
}